// Round 1
// baseline (764.786 us; speedup 1.0000x reference)
//
#include <hip/hip_runtime.h>
#include <math.h>

// Problem constants (from reference): B=8, Cin=32, Cout=32, S=256,
// REGION=64, OVERLAP=0 -> 4x4 regions, MAX_M=16.
#define NB 8
#define CIN 32
#define COUT 32
#define SS 256
#define REG 64
#define NMAX 16

// Workspace layout (bytes):
//   0      : avg[128]  float   [r*8+b]
//   1024   : nm[128]   int32   [b*16+r]
//   2048   : used[32]  int32
//   4096   : cyc64[64] float
//   4352   : cycN[136] float   (cas(2*pi*j/n), offset n*(n-1)/2)
//   8192   : Y[...]    float   dht2 of weights per used n, 6.13 MB
//   8  MB  : Xe        float   [br][i][256], 4 MB
//   12 MB  : Xo        float   4 MB
//   16 MB  : Z         float   [br][o][256], 4 MB
#define AVG_OFF   0
#define NM_OFF    1024
#define USED_OFF  2048
#define C64_OFF   4096
#define CN_OFF    4352
#define Y_OFF     8192
#define XE_OFF    (8u << 20)
#define XO_OFF    (12u << 20)
#define Z_OFF     (16u << 20)

__global__ void k_tables(float* __restrict__ cyc64, float* __restrict__ cycN) {
    int t = threadIdx.x;
    if (t < 64) {
        double a = (2.0 * M_PI / 64.0) * (double)t;
        cyc64[t] = (float)(cos(a) + sin(a));
    }
    if (t == 0) {
        int off = 0;
        for (int n = 1; n <= NMAX; ++n) {
            for (int j = 0; j < n; ++j) {
                double a = (2.0 * M_PI / (double)n) * (double)j;
                cycN[off + j] = (float)(cos(a) + sin(a));
            }
            off += n;
        }
    }
}

// One block per (r, b): mean of 64x64 region of error signal, fp64 accum.
__global__ void k_avg(const float* __restrict__ err, float* __restrict__ avg) {
    int r = blockIdx.x, b = blockIdx.y;
    int ri = r >> 2, rj = r & 3;
    const float* base = err + ((size_t)b * SS + ri * REG) * SS + rj * REG;
    int t = threadIdx.x;
    double s = 0.0;
    for (int it = 0; it < 16; ++it) {
        int u = it * 4 + (t >> 6);
        int v = t & 63;
        s += (double)base[(size_t)u * SS + v];
    }
    __shared__ double sm[256];
    sm[t] = s;
    __syncthreads();
    for (int w = 128; w > 0; w >>= 1) {
        if (t < w) sm[t] += sm[t + w];
        __syncthreads();
    }
    if (t == 0) avg[r * 8 + b] = (float)(sm[0] / 4096.0);
}

// Single block: per-region batch min/max normalize -> nm, plus used-n flags.
__global__ void k_nm(const float* __restrict__ avg, int* __restrict__ nm,
                     int* __restrict__ used) {
    int t = threadIdx.x;
    if (t < 32) used[t] = 0;
    __syncthreads();
    if (t < 16) {
        int r = t;
        float mn = avg[r * 8], mx = mn;
        for (int b = 1; b < NB; ++b) {
            float v = avg[r * 8 + b];
            mn = fminf(mn, v);
            mx = fmaxf(mx, v);
        }
        float d = mx - mn;
        bool ok = ((double)d > 1e-8);
        for (int b = 0; b < NB; ++b) {
            float norm = ok ? (avg[r * 8 + b] - mn) / d : 0.0f;
            float tt = norm * 15.0f;
            int nv = (int)tt + 1;
            if (nv > NMAX) nv = NMAX;
            nm[b * 16 + r] = nv;
            atomicOr(&used[nv], 1);
        }
    }
}

// One block per (i, r, b): 16-corner separable DHT of the 64x64 region,
// then flattened-n^2 dht2, then Xe/Xo split. 256 threads.
__global__ void k_fwd(const float* __restrict__ x, const int* __restrict__ nm,
                      const float* __restrict__ cyc64, const float* __restrict__ cycN,
                      float* __restrict__ Xe, float* __restrict__ Xo) {
    int i = blockIdx.x, r = blockIdx.y, b = blockIdx.z;
    int n = nm[b * 16 + r];
    int nn = n * n;
    int ri = r >> 2, rj = r & 3;
    int t = threadIdx.x;

    __shared__ float R[64 * 64];
    __shared__ float M1[16 * 65];  // padded stride 65 to dodge bank conflicts
    __shared__ float H[256];
    __shared__ float X[256];

    const float* base = x + (((size_t)(b * CIN + i)) * SS + ri * REG) * SS + rj * REG;
    for (int it = 0; it < 16; ++it) {
        int u = it * 4 + (t >> 6), v = t & 63;
        R[u * 64 + v] = base[(size_t)u * SS + v];
    }
    __syncthreads();

    // M1[p][v] = sum_u cas(2pi*p*u/64) * R[u][v], p < n
    for (int m = t; m < n * 64; m += 256) {
        int p = m >> 6, v = m & 63;
        float acc = 0.f;
        int idx = 0;
        for (int u = 0; u < 64; ++u) {
            acc += cyc64[idx] * R[u * 64 + v];
            idx = (idx + p) & 63;
        }
        M1[p * 65 + v] = acc;
    }
    __syncthreads();

    // H[p*n+q] = sum_v M1[p][v] * cas(2pi*q*v/64)
    if (t < nn) {
        int p = t / n, q = t - (t / n) * n;
        float acc = 0.f;
        int idx = 0;
        for (int v = 0; v < 64; ++v) {
            acc += cyc64[idx] * M1[p * 65 + v];
            idx = (idx + q) & 63;
        }
        H[t] = acc;
    }
    __syncthreads();

    // X[k] = sum_{u,v<n} H[u*n+v] * cas(2pi*((p*u+q*v) mod n)/n)
    if (t < nn) {
        int p = t / n, q = t - (t / n) * n;
        const float* cn = cycN + (n * (n - 1)) / 2;
        float acc = 0.f;
        int pu = 0;
        for (int u = 0; u < n; ++u) {
            int idx = pu;
            for (int v = 0; v < n; ++v) {
                acc += H[u * n + v] * cn[idx];
                idx += q; if (idx >= n) idx -= n;
            }
            pu += p; if (pu >= n) pu -= n;
        }
        X[t] = acc;
    }
    __syncthreads();

    if (t < nn) {
        int fk = (t == 0) ? 0 : nn - t;
        float a = X[t], c = X[fk];
        size_t o = (((size_t)(b * 16 + r)) * CIN + i) * 256 + t;
        Xe[o] = 0.5f * (a + c);
        Xo[o] = 0.5f * (a - c);
    }
}

// dht2 of weights[:, :, :n, :n] for each used n. grid (1024, 16).
__global__ void k_wt(const float* __restrict__ wts, const int* __restrict__ used,
                     const float* __restrict__ cycN, float* __restrict__ Y) {
    int n = blockIdx.y + 1;
    if (!used[n]) return;
    int io = blockIdx.x;
    int t = threadIdx.x;
    __shared__ float Wt[256];
    Wt[t] = wts[(size_t)io * 256 + t];
    __syncthreads();
    int nn = n * n;
    if (t < nn) {
        int p = t / n, q = t - (t / n) * n;
        const float* cn = cycN + (n * (n - 1)) / 2;
        float acc = 0.f;
        int pu = 0;
        for (int u = 0; u < n; ++u) {
            int idx = pu;
            for (int v = 0; v < n; ++v) {
                acc += Wt[u * 16 + v] * cn[idx];
                idx += q; if (idx >= n) idx -= n;
            }
            pu += p; if (pu >= n) pu -= n;
        }
        int m = n - 1;
        int ps2 = m * (m + 1) * (2 * m + 1) / 6;  // sum of squares 1..m
        Y[(size_t)1024 * ps2 + (size_t)io * nn + t] = acc;
    }
}

// Z[o,k] = sum_i Xe[i,k]*Y[io,k] + Xo[i,k]*Y[io,flip(k)]. One block per (b,r).
__global__ void k_z(const float* __restrict__ Xe, const float* __restrict__ Xo,
                    const float* __restrict__ Y, const int* __restrict__ nm,
                    float* __restrict__ Z) {
    int br = blockIdx.x;
    int b = br >> 4, r = br & 15;
    int n = nm[b * 16 + r];
    int nn = n * n;
    int t = threadIdx.x;
    if (t >= nn) return;
    int m = n - 1;
    int ps2 = m * (m + 1) * (2 * m + 1) / 6;
    const float* Yb = Y + (size_t)1024 * ps2;
    int fk = (t == 0) ? 0 : nn - t;
    float acc[COUT];
#pragma unroll
    for (int o = 0; o < COUT; ++o) acc[o] = 0.f;
    size_t xbase = (size_t)br * CIN * 256;
    for (int i = 0; i < CIN; ++i) {
        float xe = Xe[xbase + i * 256 + t];
        float xo = Xo[xbase + i * 256 + t];
        const float* yi = Yb + (size_t)(i * COUT) * nn;
#pragma unroll
        for (int o = 0; o < COUT; ++o) {
            acc[o] += xe * yi[o * nn + t] + xo * yi[o * nn + fk];
        }
    }
    size_t zbase = (size_t)br * COUT * 256;
#pragma unroll
    for (int o = 0; o < COUT; ++o) Z[zbase + o * 256 + t] = acc[o];
}

// One block per (o, r, b): inverse dht2 (/n^2), then n->64 separable
// expansion (/4096), write the 64x64 output region.
__global__ void k_out(const float* __restrict__ Z, const int* __restrict__ nm,
                      const float* __restrict__ cyc64, const float* __restrict__ cycN,
                      float* __restrict__ out) {
    int o = blockIdx.x, r = blockIdx.y, b = blockIdx.z;
    int n = nm[b * 16 + r];
    int nn = n * n;
    int t = threadIdx.x;
    int br = b * 16 + r;

    __shared__ float Zs[256];
    __shared__ float Bk[256];
    __shared__ float E1[16 * 64];

    if (t < nn) Zs[t] = Z[((size_t)br * COUT + o) * 256 + t];
    __syncthreads();

    // Bk[k] = (1/n^2) * sum_{k2} Zs[k2] * cas(2pi*((p*u+q*v) mod n)/n)
    if (t < nn) {
        int p = t / n, q = t - (t / n) * n;
        const float* cn = cycN + (n * (n - 1)) / 2;
        float acc = 0.f;
        int pu = 0;
        for (int u = 0; u < n; ++u) {
            int idx = pu;
            for (int v = 0; v < n; ++v) {
                acc += Zs[u * n + v] * cn[idx];
                idx += q; if (idx >= n) idx -= n;
            }
            pu += p; if (pu >= n) pu -= n;
        }
        Bk[t] = acc / (float)nn;
    }
    __syncthreads();

    // E1[p][v] = sum_q Bk[p*n+q] * cas(2pi*q*v/64)
    for (int mm = t; mm < n * 64; mm += 256) {
        int p = mm >> 6, v = mm & 63;
        float acc = 0.f;
        int idx = 0;
        for (int q = 0; q < n; ++q) {
            acc += Bk[p * n + q] * cyc64[idx];
            idx = (idx + v) & 63;
        }
        E1[p * 64 + v] = acc;
    }
    __syncthreads();

    int ri = r >> 2, rj = r & 3;
    float* ob = out + (((size_t)(b * COUT + o)) * SS + ri * REG) * SS + rj * REG;
    const float inv = 1.0f / 4096.0f;
    for (int it = 0; it < 16; ++it) {
        int u = it * 4 + (t >> 6), v = t & 63;
        float acc = 0.f;
        int idx = 0;
        for (int p = 0; p < n; ++p) {
            acc += E1[p * 64 + v] * cyc64[idx];
            idx = (idx + u) & 63;
        }
        ob[(size_t)u * SS + v] = acc * inv;
    }
}

extern "C" void kernel_launch(void* const* d_in, const int* in_sizes, int n_in,
                              void* d_out, int out_size, void* d_ws, size_t ws_size,
                              hipStream_t stream) {
    const float* x   = (const float*)d_in[0];
    const float* err = (const float*)d_in[1];
    const float* wts = (const float*)d_in[2];
    float* out = (float*)d_out;
    char* ws = (char*)d_ws;

    float* avg   = (float*)(ws + AVG_OFF);
    int*   nm    = (int*)  (ws + NM_OFF);
    int*   used  = (int*)  (ws + USED_OFF);
    float* cyc64 = (float*)(ws + C64_OFF);
    float* cycN  = (float*)(ws + CN_OFF);
    float* Y     = (float*)(ws + Y_OFF);
    float* Xe    = (float*)(ws + XE_OFF);
    float* Xo    = (float*)(ws + XO_OFF);
    float* Z     = (float*)(ws + Z_OFF);

    k_tables<<<1, 64, 0, stream>>>(cyc64, cycN);
    k_avg<<<dim3(16, NB), 256, 0, stream>>>(err, avg);
    k_nm<<<1, 32, 0, stream>>>(avg, nm, used);
    k_fwd<<<dim3(CIN, 16, NB), 256, 0, stream>>>(x, nm, cyc64, cycN, Xe, Xo);
    k_wt<<<dim3(CIN * COUT, NMAX), 256, 0, stream>>>(wts, used, cycN, Y);
    k_z<<<128, 256, 0, stream>>>(Xe, Xo, Y, nm, Z);
    k_out<<<dim3(COUT, 16, NB), 256, 0, stream>>>(Z, nm, cyc64, cycN, out);
}

// Round 2
// 498.060 us; speedup vs baseline: 1.5355x; 1.5355x over previous
//
#include <hip/hip_runtime.h>
#include <math.h>

// Problem constants (from reference): B=8, Cin=32, Cout=32, S=256,
// REGION=64, OVERLAP=0 -> 4x4 regions, MAX_M=16.
#define NB 8
#define CIN 32
#define COUT 32
#define SS 256
#define REG 64
#define NMAX 16

// Workspace layout (bytes):
//   0      : avg[128]  float   [r*8+b]
//   1024   : nm[128]   int32   [b*16+r]
//   2048   : used[32]  int32
//   4096   : cyc64[64] float
//   4352   : cycN[136] float   (cas(2*pi*j/n), offset n*(n-1)/2)
//   8192   : Y[...]    float   dht2 of weights per used n, 6.13 MB
//   8  MB  : Xe        float   [br][i][256], 4 MB
//   12 MB  : Xo        float   4 MB
//   16 MB  : Z         float   [br][o][256], 4 MB
#define AVG_OFF   0
#define NM_OFF    1024
#define USED_OFF  2048
#define C64_OFF   4096
#define CN_OFF    4352
#define Y_OFF     8192
#define XE_OFF    (8u << 20)
#define XO_OFF    (12u << 20)
#define Z_OFF     (16u << 20)

__global__ void k_tables(float* __restrict__ cyc64, float* __restrict__ cycN) {
    int t = threadIdx.x;
    if (t < 64) {
        double a = (2.0 * M_PI / 64.0) * (double)t;
        cyc64[t] = (float)(cos(a) + sin(a));
    }
    if (t == 0) {
        int off = 0;
        for (int n = 1; n <= NMAX; ++n) {
            for (int j = 0; j < n; ++j) {
                double a = (2.0 * M_PI / (double)n) * (double)j;
                cycN[off + j] = (float)(cos(a) + sin(a));
            }
            off += n;
        }
    }
}

// One block per (r, b): mean of 64x64 region of error signal, fp64 accum.
__global__ void k_avg(const float* __restrict__ err, float* __restrict__ avg) {
    int r = blockIdx.x, b = blockIdx.y;
    int ri = r >> 2, rj = r & 3;
    const float* base = err + ((size_t)b * SS + ri * REG) * SS + rj * REG;
    int t = threadIdx.x;
    double s = 0.0;
    for (int it = 0; it < 16; ++it) {
        int u = it * 4 + (t >> 6);
        int v = t & 63;
        s += (double)base[(size_t)u * SS + v];
    }
    __shared__ double sm[256];
    sm[t] = s;
    __syncthreads();
    for (int w = 128; w > 0; w >>= 1) {
        if (t < w) sm[t] += sm[t + w];
        __syncthreads();
    }
    if (t == 0) avg[r * 8 + b] = (float)(sm[0] / 4096.0);
}

// Single block: per-region batch min/max normalize -> nm, plus used-n flags.
__global__ void k_nm(const float* __restrict__ avg, int* __restrict__ nm,
                     int* __restrict__ used) {
    int t = threadIdx.x;
    if (t < 32) used[t] = 0;
    __syncthreads();
    if (t < 16) {
        int r = t;
        float mn = avg[r * 8], mx = mn;
        for (int b = 1; b < NB; ++b) {
            float v = avg[r * 8 + b];
            mn = fminf(mn, v);
            mx = fmaxf(mx, v);
        }
        float d = mx - mn;
        bool ok = ((double)d > 1e-8);
        for (int b = 0; b < NB; ++b) {
            float norm = ok ? (avg[r * 8 + b] - mn) / d : 0.0f;
            float tt = norm * 15.0f;
            int nv = (int)tt + 1;
            if (nv > NMAX) nv = NMAX;
            nm[b * 16 + r] = nv;
            atomicOr(&used[nv], 1);
        }
    }
}

// One block per (i, r, b): 16-corner separable DHT of the 64x64 region,
// then flattened-n^2 dht2, then Xe/Xo split. 256 threads.
__global__ void k_fwd(const float* __restrict__ x, const int* __restrict__ nm,
                      const float* __restrict__ cyc64, const float* __restrict__ cycN,
                      float* __restrict__ Xe, float* __restrict__ Xo) {
    int i = blockIdx.x, r = blockIdx.y, b = blockIdx.z;
    int n = nm[b * 16 + r];
    int nn = n * n;
    int ri = r >> 2, rj = r & 3;
    int t = threadIdx.x;

    __shared__ float R[64 * 64];
    __shared__ float M1[16 * 65];  // padded stride 65 to dodge bank conflicts
    __shared__ float H[256];
    __shared__ float X[256];

    const float* base = x + (((size_t)(b * CIN + i)) * SS + ri * REG) * SS + rj * REG;
    for (int it = 0; it < 16; ++it) {
        int u = it * 4 + (t >> 6), v = t & 63;
        R[u * 64 + v] = base[(size_t)u * SS + v];
    }
    __syncthreads();

    // M1[p][v] = sum_u cas(2pi*p*u/64) * R[u][v], p < n
    for (int m = t; m < n * 64; m += 256) {
        int p = m >> 6, v = m & 63;
        float acc = 0.f;
        int idx = 0;
        for (int u = 0; u < 64; ++u) {
            acc += cyc64[idx] * R[u * 64 + v];
            idx = (idx + p) & 63;
        }
        M1[p * 65 + v] = acc;
    }
    __syncthreads();

    // H[p*n+q] = sum_v M1[p][v] * cas(2pi*q*v/64)
    if (t < nn) {
        int p = t / n, q = t - (t / n) * n;
        float acc = 0.f;
        int idx = 0;
        for (int v = 0; v < 64; ++v) {
            acc += cyc64[idx] * M1[p * 65 + v];
            idx = (idx + q) & 63;
        }
        H[t] = acc;
    }
    __syncthreads();

    // X[k] = sum_{u,v<n} H[u*n+v] * cas(2pi*((p*u+q*v) mod n)/n)
    if (t < nn) {
        int p = t / n, q = t - (t / n) * n;
        const float* cn = cycN + (n * (n - 1)) / 2;
        float acc = 0.f;
        int pu = 0;
        for (int u = 0; u < n; ++u) {
            int idx = pu;
            for (int v = 0; v < n; ++v) {
                acc += H[u * n + v] * cn[idx];
                idx += q; if (idx >= n) idx -= n;
            }
            pu += p; if (pu >= n) pu -= n;
        }
        X[t] = acc;
    }
    __syncthreads();

    if (t < nn) {
        int fk = (t == 0) ? 0 : nn - t;
        float a = X[t], c = X[fk];
        size_t o = (((size_t)(b * 16 + r)) * CIN + i) * 256 + t;
        Xe[o] = 0.5f * (a + c);
        Xo[o] = 0.5f * (a - c);
    }
}

// dht2 of weights[:, :, :n, :n] for each used n. grid (1024, 16).
__global__ void k_wt(const float* __restrict__ wts, const int* __restrict__ used,
                     const float* __restrict__ cycN, float* __restrict__ Y) {
    int n = blockIdx.y + 1;
    if (!used[n]) return;
    int io = blockIdx.x;
    int t = threadIdx.x;
    __shared__ float Wt[256];
    Wt[t] = wts[(size_t)io * 256 + t];
    __syncthreads();
    int nn = n * n;
    if (t < nn) {
        int p = t / n, q = t - (t / n) * n;
        const float* cn = cycN + (n * (n - 1)) / 2;
        float acc = 0.f;
        int pu = 0;
        for (int u = 0; u < n; ++u) {
            int idx = pu;
            for (int v = 0; v < n; ++v) {
                acc += Wt[u * 16 + v] * cn[idx];
                idx += q; if (idx >= n) idx -= n;
            }
            pu += p; if (pu >= n) pu -= n;
        }
        int m = n - 1;
        int ps2 = m * (m + 1) * (2 * m + 1) / 6;  // sum of squares 1..m
        Y[(size_t)1024 * ps2 + (size_t)io * nn + t] = acc;
    }
}

// Z[o,k] = sum_i Xe[i,k]*Y[io,k] + Xo[i,k]*Y[io,flip(k)].
// grid (8, 128): blockIdx.x selects a group of 4 outputs, blockIdx.y = (b,r).
// 1024 blocks -> ~4 blocks/CU; fixes the 2.4% occupancy of the old version.
__global__ void k_z(const float* __restrict__ Xe, const float* __restrict__ Xo,
                    const float* __restrict__ Y, const int* __restrict__ nm,
                    float* __restrict__ Z) {
    int br = blockIdx.y;
    int og = blockIdx.x * 4;
    int b = br >> 4, r = br & 15;
    int n = nm[b * 16 + r];
    int nn = n * n;
    int t = threadIdx.x;
    if (t >= nn) return;
    int m = n - 1;
    int ps2 = m * (m + 1) * (2 * m + 1) / 6;
    const float* Yb = Y + (size_t)1024 * ps2;
    int fk = (t == 0) ? 0 : nn - t;
    float acc[4] = {0.f, 0.f, 0.f, 0.f};
    size_t xbase = (size_t)br * CIN * 256;
    for (int i = 0; i < CIN; ++i) {
        float xe = Xe[xbase + i * 256 + t];
        float xo = Xo[xbase + i * 256 + t];
        const float* yi = Yb + (size_t)(i * COUT + og) * nn;
#pragma unroll
        for (int oo = 0; oo < 4; ++oo) {
            acc[oo] += xe * yi[oo * nn + t] + xo * yi[oo * nn + fk];
        }
    }
    size_t zbase = (size_t)br * COUT * 256;
#pragma unroll
    for (int oo = 0; oo < 4; ++oo) Z[zbase + (og + oo) * 256 + t] = acc[oo];
}

// One block per (o, r, b): inverse dht2 (/n^2), then n->64 separable
// expansion (/4096), write the 64x64 output region.
__global__ void k_out(const float* __restrict__ Z, const int* __restrict__ nm,
                      const float* __restrict__ cyc64, const float* __restrict__ cycN,
                      float* __restrict__ out) {
    int o = blockIdx.x, r = blockIdx.y, b = blockIdx.z;
    int n = nm[b * 16 + r];
    int nn = n * n;
    int t = threadIdx.x;
    int br = b * 16 + r;

    __shared__ float Zs[256];
    __shared__ float Bk[256];
    __shared__ float E1[16 * 64];

    if (t < nn) Zs[t] = Z[((size_t)br * COUT + o) * 256 + t];
    __syncthreads();

    // Bk[k] = (1/n^2) * sum_{k2} Zs[k2] * cas(2pi*((p*u+q*v) mod n)/n)
    if (t < nn) {
        int p = t / n, q = t - (t / n) * n;
        const float* cn = cycN + (n * (n - 1)) / 2;
        float acc = 0.f;
        int pu = 0;
        for (int u = 0; u < n; ++u) {
            int idx = pu;
            for (int v = 0; v < n; ++v) {
                acc += Zs[u * n + v] * cn[idx];
                idx += q; if (idx >= n) idx -= n;
            }
            pu += p; if (pu >= n) pu -= n;
        }
        Bk[t] = acc / (float)nn;
    }
    __syncthreads();

    // E1[p][v] = sum_q Bk[p*n+q] * cas(2pi*q*v/64)
    for (int mm = t; mm < n * 64; mm += 256) {
        int p = mm >> 6, v = mm & 63;
        float acc = 0.f;
        int idx = 0;
        for (int q = 0; q < n; ++q) {
            acc += Bk[p * n + q] * cyc64[idx];
            idx = (idx + v) & 63;
        }
        E1[p * 64 + v] = acc;
    }
    __syncthreads();

    int ri = r >> 2, rj = r & 3;
    float* ob = out + (((size_t)(b * COUT + o)) * SS + ri * REG) * SS + rj * REG;
    const float inv = 1.0f / 4096.0f;
    for (int it = 0; it < 16; ++it) {
        int u = it * 4 + (t >> 6), v = t & 63;
        float acc = 0.f;
        int idx = 0;
        for (int p = 0; p < n; ++p) {
            acc += E1[p * 64 + v] * cyc64[idx];
            idx = (idx + u) & 63;
        }
        ob[(size_t)u * SS + v] = acc * inv;
    }
}

extern "C" void kernel_launch(void* const* d_in, const int* in_sizes, int n_in,
                              void* d_out, int out_size, void* d_ws, size_t ws_size,
                              hipStream_t stream) {
    const float* x   = (const float*)d_in[0];
    const float* err = (const float*)d_in[1];
    const float* wts = (const float*)d_in[2];
    float* out = (float*)d_out;
    char* ws = (char*)d_ws;

    float* avg   = (float*)(ws + AVG_OFF);
    int*   nm    = (int*)  (ws + NM_OFF);
    int*   used  = (int*)  (ws + USED_OFF);
    float* cyc64 = (float*)(ws + C64_OFF);
    float* cycN  = (float*)(ws + CN_OFF);
    float* Y     = (float*)(ws + Y_OFF);
    float* Xe    = (float*)(ws + XE_OFF);
    float* Xo    = (float*)(ws + XO_OFF);
    float* Z     = (float*)(ws + Z_OFF);

    k_tables<<<1, 64, 0, stream>>>(cyc64, cycN);
    k_avg<<<dim3(16, NB), 256, 0, stream>>>(err, avg);
    k_nm<<<1, 32, 0, stream>>>(avg, nm, used);
    k_fwd<<<dim3(CIN, 16, NB), 256, 0, stream>>>(x, nm, cyc64, cycN, Xe, Xo);
    k_wt<<<dim3(CIN * COUT, NMAX), 256, 0, stream>>>(wts, used, cycN, Y);
    k_z<<<dim3(8, 128), 256, 0, stream>>>(Xe, Xo, Y, nm, Z);
    k_out<<<dim3(COUT, 16, NB), 256, 0, stream>>>(Z, nm, cyc64, cycN, out);
}

// Round 3
// 224.741 us; speedup vs baseline: 3.4030x; 2.2161x over previous
//
#include <hip/hip_runtime.h>
#include <math.h>

// Problem constants (from reference): B=8, Cin=32, Cout=32, S=256,
// REGION=64, OVERLAP=0 -> 4x4 regions, MAX_M=16.
#define NB 8
#define CIN 32
#define COUT 32
#define SS 256
#define REG 64
#define NMAX 16

// Workspace layout (bytes):
#define AVG_OFF   0
#define NM_OFF    1024
#define USED_OFF  2048
#define C64_OFF   4096
#define CN_OFF    4352
#define Y_OFF     8192
#define XE_OFF    (8u << 20)
#define XO_OFF    (12u << 20)
#define Z_OFF     (16u << 20)

__global__ void k_tables(float* __restrict__ cyc64, float* __restrict__ cycN) {
    int t = threadIdx.x;
    if (t < 64) {
        double a = (2.0 * M_PI / 64.0) * (double)t;
        cyc64[t] = (float)(cos(a) + sin(a));
    }
    if (t == 0) {
        int off = 0;
        for (int n = 1; n <= NMAX; ++n) {
            for (int j = 0; j < n; ++j) {
                double a = (2.0 * M_PI / (double)n) * (double)j;
                cycN[off + j] = (float)(cos(a) + sin(a));
            }
            off += n;
        }
    }
}

// One block per (r, b): mean of 64x64 region of error signal, fp64 accum.
__global__ void k_avg(const float* __restrict__ err, float* __restrict__ avg) {
    int r = blockIdx.x, b = blockIdx.y;
    int ri = r >> 2, rj = r & 3;
    const float* base = err + ((size_t)b * SS + ri * REG) * SS + rj * REG;
    int t = threadIdx.x;
    double s = 0.0;
    for (int it = 0; it < 16; ++it) {
        int u = it * 4 + (t >> 6);
        int v = t & 63;
        s += (double)base[(size_t)u * SS + v];
    }
    __shared__ double sm[256];
    sm[t] = s;
    __syncthreads();
    for (int w = 128; w > 0; w >>= 1) {
        if (t < w) sm[t] += sm[t + w];
        __syncthreads();
    }
    if (t == 0) avg[r * 8 + b] = (float)(sm[0] / 4096.0);
}

// Single block: per-region batch min/max normalize -> nm, plus used-n flags.
__global__ void k_nm(const float* __restrict__ avg, int* __restrict__ nm,
                     int* __restrict__ used) {
    int t = threadIdx.x;
    if (t < 32) used[t] = 0;
    __syncthreads();
    if (t < 16) {
        int r = t;
        float mn = avg[r * 8], mx = mn;
        for (int b = 1; b < NB; ++b) {
            float v = avg[r * 8 + b];
            mn = fminf(mn, v);
            mx = fmaxf(mx, v);
        }
        float d = mx - mn;
        bool ok = ((double)d > 1e-8);
        for (int b = 0; b < NB; ++b) {
            float norm = ok ? (avg[r * 8 + b] - mn) / d : 0.0f;
            float tt = norm * 15.0f;
            int nv = (int)tt + 1;
            if (nv > NMAX) nv = NMAX;
            nm[b * 16 + r] = nv;
            atomicOr(&used[nv], 1);
        }
    }
}

// One block per (i, r, b): n-corner separable DHT of the 64x64 region, then
// true n x n dht2 via row-column + correction, then Xe/Xo split. 256 threads.
// All cas tables LDS-resident; heavy stage uses float4 LDS reads.
__global__ void k_fwd(const float* __restrict__ x, const int* __restrict__ nm,
                      const float* __restrict__ cyc64, const float* __restrict__ cycN,
                      float* __restrict__ Xe, float* __restrict__ Xo) {
    int i = blockIdx.x, r = blockIdx.y, b = blockIdx.z;
    int n = nm[b * 16 + r];
    int nn = n * n;
    int ri = r >> 2, rj = r & 3;
    int t = threadIdx.x;

    __shared__ __align__(16) float R[64 * 64];
    __shared__ __align__(16) float M1[16 * 68];   // stride 68: avoids p-group write conflicts
    __shared__ float H[256];
    __shared__ float T1[256];
    __shared__ float T2[256];
    __shared__ float cyc64L[64];
    __shared__ float cnL[16];

    if (t < 64) cyc64L[t] = cyc64[t];
    if (t < n)  cnL[t] = cycN[(n * (n - 1)) / 2 + t];

    const float* base = x + (((size_t)(b * CIN + i)) * SS + ri * REG) * SS + rj * REG;
    float4* R4 = (float4*)R;
    {
        int u0 = t >> 4, c4 = t & 15;
        for (int it = 0; it < 4; ++it) {
            int u = it * 16 + u0;
            R4[u * 16 + c4] = *(const float4*)(base + (size_t)u * SS + c4 * 4);
        }
    }
    __syncthreads();

    // stage 1: M1[p][v] = sum_u cas64(p*u) * R[u][v], p < n. float4 over v.
    {
        int p1 = t >> 4, vg = t & 15;
        if (p1 < n) {
            float4 acc = {0.f, 0.f, 0.f, 0.f};
            int idx = 0;
            for (int u = 0; u < 64; ++u) {
                float c = cyc64L[idx]; idx = (idx + p1) & 63;
                float4 rv = R4[u * 16 + vg];
                acc.x += c * rv.x; acc.y += c * rv.y;
                acc.z += c * rv.z; acc.w += c * rv.w;
            }
            *(float4*)&M1[p1 * 68 + vg * 4] = acc;
        }
    }
    __syncthreads();

    int p = 0, q = 0;
    if (t < nn) { p = t / n; q = t - p * n; }

    // stage 2: H[p][q] = sum_v M1[p][v] * cas64(q*v)
    if (t < nn) {
        float acc = 0.f;
        int idx = 0;
        for (int v = 0; v < 64; ++v) {
            acc += M1[p * 68 + v] * cyc64L[idx];
            idx = (idx + q) & 63;
        }
        H[t] = acc;
    }
    __syncthreads();

    // stage 3: true 2-D DHT of H (n x n) = row-column + correction (2n^3, not n^4)
    if (t < nn) {
        float acc = 0.f;
        int idx = 0;
        for (int v = 0; v < n; ++v) {
            acc += H[p * n + v] * cnL[idx];
            idx += q; if (idx >= n) idx -= n;
        }
        T1[p * n + q] = acc;   // T1[u][q]
    }
    __syncthreads();
    if (t < nn) {
        float acc = 0.f;
        int idx = 0;
        for (int u = 0; u < n; ++u) {
            acc += T1[u * n + q] * cnL[idx];
            idx += p; if (idx >= n) idx -= n;
        }
        T2[t] = acc;           // separable transform
    }
    __syncthreads();
    if (t < nn) {
        int pf = (p == 0) ? 0 : n - p;
        int qf = (q == 0) ? 0 : n - q;
        H[t] = 0.5f * (T2[p * n + q] + T2[pf * n + q] + T2[p * n + qf] - T2[pf * n + qf]);
    }
    __syncthreads();

    if (t < nn) {
        int fk = (t == 0) ? 0 : nn - t;
        float a = H[t], c = H[fk];
        size_t o = (((size_t)(b * 16 + r)) * CIN + i) * 256 + t;
        Xe[o] = 0.5f * (a + c);
        Xo[o] = 0.5f * (a - c);
    }
}

// dht2 of weights[:, :, :n, :n] for each used n, row-column + correction.
__global__ void k_wt(const float* __restrict__ wts, const int* __restrict__ used,
                     const float* __restrict__ cycN, float* __restrict__ Y) {
    int n = blockIdx.y + 1;
    if (!used[n]) return;
    int io = blockIdx.x;
    int t = threadIdx.x;
    int nn = n * n;
    __shared__ float Wt[256];
    __shared__ float T1[256];
    __shared__ float T2[256];
    __shared__ float cnL[16];
    Wt[t] = wts[(size_t)io * 256 + t];
    if (t < n) cnL[t] = cycN[(n * (n - 1)) / 2 + t];
    __syncthreads();
    int p = 0, q = 0;
    if (t < nn) { p = t / n; q = t - p * n; }
    if (t < nn) {
        float acc = 0.f;
        int idx = 0;
        for (int v = 0; v < n; ++v) {
            acc += Wt[p * 16 + v] * cnL[idx];
            idx += q; if (idx >= n) idx -= n;
        }
        T1[p * n + q] = acc;
    }
    __syncthreads();
    if (t < nn) {
        float acc = 0.f;
        int idx = 0;
        for (int u = 0; u < n; ++u) {
            acc += T1[u * n + q] * cnL[idx];
            idx += p; if (idx >= n) idx -= n;
        }
        T2[t] = acc;
    }
    __syncthreads();
    if (t < nn) {
        int pf = (p == 0) ? 0 : n - p;
        int qf = (q == 0) ? 0 : n - q;
        float v = 0.5f * (T2[p * n + q] + T2[pf * n + q] + T2[p * n + qf] - T2[pf * n + qf]);
        int m = n - 1;
        int ps2 = m * (m + 1) * (2 * m + 1) / 6;  // sum of squares 1..m
        Y[(size_t)1024 * ps2 + (size_t)io * nn + t] = v;
    }
}

// Z[o,k] = sum_i Xe[i,k]*Y[io,k] + Xo[i,k]*Y[io,flip(k)].
// grid (8, 128): blockIdx.x = group of 4 outputs, blockIdx.y = (b,r).
__global__ void k_z(const float* __restrict__ Xe, const float* __restrict__ Xo,
                    const float* __restrict__ Y, const int* __restrict__ nm,
                    float* __restrict__ Z) {
    int br = blockIdx.y;
    int og = blockIdx.x * 4;
    int b = br >> 4, r = br & 15;
    int n = nm[b * 16 + r];
    int nn = n * n;
    int t = threadIdx.x;
    if (t >= nn) return;
    int m = n - 1;
    int ps2 = m * (m + 1) * (2 * m + 1) / 6;
    const float* Yb = Y + (size_t)1024 * ps2;
    int fk = (t == 0) ? 0 : nn - t;
    float acc[4] = {0.f, 0.f, 0.f, 0.f};
    size_t xbase = (size_t)br * CIN * 256;
    for (int i = 0; i < CIN; ++i) {
        float xe = Xe[xbase + i * 256 + t];
        float xo = Xo[xbase + i * 256 + t];
        const float* yi = Yb + (size_t)(i * COUT + og) * nn;
#pragma unroll
        for (int oo = 0; oo < 4; ++oo) {
            acc[oo] += xe * yi[oo * nn + t] + xo * yi[oo * nn + fk];
        }
    }
    size_t zbase = (size_t)br * COUT * 256;
#pragma unroll
    for (int oo = 0; oo < 4; ++oo) Z[zbase + (og + oo) * 256 + t] = acc[oo];
}

// One block per (o, r, b): inverse dht2 via row-column + correction (/n^2),
// then n->64 separable expansion (/4096), float4 heavy stage, write region.
__global__ void k_out(const float* __restrict__ Z, const int* __restrict__ nm,
                      const float* __restrict__ cyc64, const float* __restrict__ cycN,
                      float* __restrict__ out) {
    int o = blockIdx.x, r = blockIdx.y, b = blockIdx.z;
    int n = nm[b * 16 + r];
    int nn = n * n;
    int t = threadIdx.x;
    int br = b * 16 + r;

    __shared__ float Zs[256];
    __shared__ float T1[256];
    __shared__ float T2[256];
    __shared__ float Bk[256];
    __shared__ __align__(16) float E1[16 * 64];
    __shared__ float cyc64L[64];
    __shared__ float cnL[16];

    if (t < 64) cyc64L[t] = cyc64[t];
    if (t < n)  cnL[t] = cycN[(n * (n - 1)) / 2 + t];
    if (t < nn) Zs[t] = Z[((size_t)br * COUT + o) * 256 + t];
    __syncthreads();

    int p = 0, q = 0;
    if (t < nn) { p = t / n; q = t - p * n; }

    // inverse dht2 (row-column + correction), / nn
    if (t < nn) {
        float acc = 0.f;
        int idx = 0;
        for (int v = 0; v < n; ++v) {
            acc += Zs[p * n + v] * cnL[idx];
            idx += q; if (idx >= n) idx -= n;
        }
        T1[p * n + q] = acc;
    }
    __syncthreads();
    if (t < nn) {
        float acc = 0.f;
        int idx = 0;
        for (int u = 0; u < n; ++u) {
            acc += T1[u * n + q] * cnL[idx];
            idx += p; if (idx >= n) idx -= n;
        }
        T2[t] = acc;
    }
    __syncthreads();
    if (t < nn) {
        int pf = (p == 0) ? 0 : n - p;
        int qf = (q == 0) ? 0 : n - q;
        Bk[t] = 0.5f * (T2[p * n + q] + T2[pf * n + q] + T2[p * n + qf] - T2[pf * n + qf])
                / (float)nn;
    }
    __syncthreads();

    // E1[p][v] = sum_q Bk[p*n+q] * cas64(q*v)   (wave-uniform p: Bk read is broadcast)
    for (int mm = t; mm < n * 64; mm += 256) {
        int pp = mm >> 6, v = mm & 63;
        float acc = 0.f;
        int idx = 0;
        for (int qq = 0; qq < n; ++qq) {
            acc += Bk[pp * n + qq] * cyc64L[idx];
            idx = (idx + v) & 63;
        }
        E1[pp * 64 + v] = acc;
    }
    __syncthreads();

    // out[u][v] = (1/4096) sum_p E1[p][v] * cas64(p*u); float4 over v.
    int ri = r >> 2, rj = r & 3;
    float* ob = out + (((size_t)(b * COUT + o)) * SS + ri * REG) * SS + rj * REG;
    const float4* E14 = (const float4*)E1;
    const float inv = 1.0f / 4096.0f;
    int u0 = t >> 4, vg = t & 15;
    for (int it = 0; it < 4; ++it) {
        int u = it * 16 + u0;
        float4 acc = {0.f, 0.f, 0.f, 0.f};
        int idx = 0;
        for (int pp = 0; pp < n; ++pp) {
            float c = cyc64L[idx]; idx = (idx + u) & 63;
            float4 e = E14[pp * 16 + vg];
            acc.x += c * e.x; acc.y += c * e.y;
            acc.z += c * e.z; acc.w += c * e.w;
        }
        acc.x *= inv; acc.y *= inv; acc.z *= inv; acc.w *= inv;
        *(float4*)(ob + (size_t)u * SS + vg * 4) = acc;
    }
}

extern "C" void kernel_launch(void* const* d_in, const int* in_sizes, int n_in,
                              void* d_out, int out_size, void* d_ws, size_t ws_size,
                              hipStream_t stream) {
    const float* x   = (const float*)d_in[0];
    const float* err = (const float*)d_in[1];
    const float* wts = (const float*)d_in[2];
    float* out = (float*)d_out;
    char* ws = (char*)d_ws;

    float* avg   = (float*)(ws + AVG_OFF);
    int*   nm    = (int*)  (ws + NM_OFF);
    int*   used  = (int*)  (ws + USED_OFF);
    float* cyc64 = (float*)(ws + C64_OFF);
    float* cycN  = (float*)(ws + CN_OFF);
    float* Y     = (float*)(ws + Y_OFF);
    float* Xe    = (float*)(ws + XE_OFF);
    float* Xo    = (float*)(ws + XO_OFF);
    float* Z     = (float*)(ws + Z_OFF);

    k_tables<<<1, 64, 0, stream>>>(cyc64, cycN);
    k_avg<<<dim3(16, NB), 256, 0, stream>>>(err, avg);
    k_nm<<<1, 32, 0, stream>>>(avg, nm, used);
    k_fwd<<<dim3(CIN, 16, NB), 256, 0, stream>>>(x, nm, cyc64, cycN, Xe, Xo);
    k_wt<<<dim3(CIN * COUT, NMAX), 256, 0, stream>>>(wts, used, cycN, Y);
    k_z<<<dim3(8, 128), 256, 0, stream>>>(Xe, Xo, Y, nm, Z);
    k_out<<<dim3(COUT, 16, NB), 256, 0, stream>>>(Z, nm, cyc64, cycN, out);
}

// Round 4
// 178.549 us; speedup vs baseline: 4.2833x; 1.2587x over previous
//
#include <hip/hip_runtime.h>
#include <math.h>

// Problem constants (from reference): B=8, Cin=32, Cout=32, S=256,
// REGION=64, OVERLAP=0 -> 4x4 regions, MAX_M=16.
#define NB 8
#define CIN 32
#define COUT 32
#define SS 256
#define REG 64
#define NMAX 16

// Workspace layout (bytes):
#define AVG_OFF   0
#define NM_OFF    1024
#define USED_OFF  2048
#define C64_OFF   4096
#define CN_OFF    4352
#define Y_OFF     8192
#define XE_OFF    (8u << 20)
#define XO_OFF    (12u << 20)
#define Z_OFF     (16u << 20)

// One table entry per thread: t<64 -> cyc64[t]; t in [64,200) -> cycN[t-64].
// (Previous version computed all 136 cycN entries serially on thread 0 with
// f64 transcendentals -> 56 us. Parallel: one cos+sin pair per thread.)
__global__ void k_tables(float* __restrict__ cyc64, float* __restrict__ cycN) {
    int t = threadIdx.x;
    if (t < 64) {
        double a = (2.0 * M_PI / 64.0) * (double)t;
        cyc64[t] = (float)(cos(a) + sin(a));
    } else if (t < 64 + 136) {
        int e = t - 64;
        int n = 1;
        while (n * (n + 1) / 2 <= e) ++n;   // smallest n with n(n+1)/2 > e
        int j = e - n * (n - 1) / 2;
        double a = (2.0 * M_PI / (double)n) * (double)j;
        cycN[e] = (float)(cos(a) + sin(a));
    }
}

// One block per (r, b): mean of 64x64 region of error signal, fp64 accum.
__global__ void k_avg(const float* __restrict__ err, float* __restrict__ avg) {
    int r = blockIdx.x, b = blockIdx.y;
    int ri = r >> 2, rj = r & 3;
    const float* base = err + ((size_t)b * SS + ri * REG) * SS + rj * REG;
    int t = threadIdx.x;
    double s = 0.0;
    for (int it = 0; it < 16; ++it) {
        int u = it * 4 + (t >> 6);
        int v = t & 63;
        s += (double)base[(size_t)u * SS + v];
    }
    __shared__ double sm[256];
    sm[t] = s;
    __syncthreads();
    for (int w = 128; w > 0; w >>= 1) {
        if (t < w) sm[t] += sm[t + w];
        __syncthreads();
    }
    if (t == 0) avg[r * 8 + b] = (float)(sm[0] / 4096.0);
}

// Single block: per-region batch min/max normalize -> nm, plus used-n flags.
__global__ void k_nm(const float* __restrict__ avg, int* __restrict__ nm,
                     int* __restrict__ used) {
    int t = threadIdx.x;
    if (t < 32) used[t] = 0;
    __syncthreads();
    if (t < 16) {
        int r = t;
        float mn = avg[r * 8], mx = mn;
        for (int b = 1; b < NB; ++b) {
            float v = avg[r * 8 + b];
            mn = fminf(mn, v);
            mx = fmaxf(mx, v);
        }
        float d = mx - mn;
        bool ok = ((double)d > 1e-8);
        for (int b = 0; b < NB; ++b) {
            float norm = ok ? (avg[r * 8 + b] - mn) / d : 0.0f;
            float tt = norm * 15.0f;
            int nv = (int)tt + 1;
            if (nv > NMAX) nv = NMAX;
            nm[b * 16 + r] = nv;
            atomicOr(&used[nv], 1);
        }
    }
}

// One block per (i, r, b): n-corner separable DHT of the 64x64 region, then
// true n x n dht2 via row-column + correction, then Xe/Xo split. 256 threads.
// All cas tables LDS-resident; heavy stage uses float4 LDS reads.
__global__ void k_fwd(const float* __restrict__ x, const int* __restrict__ nm,
                      const float* __restrict__ cyc64, const float* __restrict__ cycN,
                      float* __restrict__ Xe, float* __restrict__ Xo) {
    int i = blockIdx.x, r = blockIdx.y, b = blockIdx.z;
    int n = nm[b * 16 + r];
    int nn = n * n;
    int ri = r >> 2, rj = r & 3;
    int t = threadIdx.x;

    __shared__ __align__(16) float R[64 * 64];
    __shared__ __align__(16) float M1[16 * 68];   // stride 68: avoids p-group write conflicts
    __shared__ float H[256];
    __shared__ float T1[256];
    __shared__ float T2[256];
    __shared__ float cyc64L[64];
    __shared__ float cnL[16];

    if (t < 64) cyc64L[t] = cyc64[t];
    if (t < n)  cnL[t] = cycN[(n * (n - 1)) / 2 + t];

    const float* base = x + (((size_t)(b * CIN + i)) * SS + ri * REG) * SS + rj * REG;
    float4* R4 = (float4*)R;
    {
        int u0 = t >> 4, c4 = t & 15;
        for (int it = 0; it < 4; ++it) {
            int u = it * 16 + u0;
            R4[u * 16 + c4] = *(const float4*)(base + (size_t)u * SS + c4 * 4);
        }
    }
    __syncthreads();

    // stage 1: M1[p][v] = sum_u cas64(p*u) * R[u][v], p < n. float4 over v.
    {
        int p1 = t >> 4, vg = t & 15;
        if (p1 < n) {
            float4 acc = {0.f, 0.f, 0.f, 0.f};
            int idx = 0;
            for (int u = 0; u < 64; ++u) {
                float c = cyc64L[idx]; idx = (idx + p1) & 63;
                float4 rv = R4[u * 16 + vg];
                acc.x += c * rv.x; acc.y += c * rv.y;
                acc.z += c * rv.z; acc.w += c * rv.w;
            }
            *(float4*)&M1[p1 * 68 + vg * 4] = acc;
        }
    }
    __syncthreads();

    int p = 0, q = 0;
    if (t < nn) { p = t / n; q = t - p * n; }

    // stage 2: H[p][q] = sum_v M1[p][v] * cas64(q*v)
    if (t < nn) {
        float acc = 0.f;
        int idx = 0;
        for (int v = 0; v < 64; ++v) {
            acc += M1[p * 68 + v] * cyc64L[idx];
            idx = (idx + q) & 63;
        }
        H[t] = acc;
    }
    __syncthreads();

    // stage 3: true 2-D DHT of H (n x n) = row-column + correction (2n^3, not n^4)
    if (t < nn) {
        float acc = 0.f;
        int idx = 0;
        for (int v = 0; v < n; ++v) {
            acc += H[p * n + v] * cnL[idx];
            idx += q; if (idx >= n) idx -= n;
        }
        T1[p * n + q] = acc;   // T1[u][q]
    }
    __syncthreads();
    if (t < nn) {
        float acc = 0.f;
        int idx = 0;
        for (int u = 0; u < n; ++u) {
            acc += T1[u * n + q] * cnL[idx];
            idx += p; if (idx >= n) idx -= n;
        }
        T2[t] = acc;           // separable transform
    }
    __syncthreads();
    if (t < nn) {
        int pf = (p == 0) ? 0 : n - p;
        int qf = (q == 0) ? 0 : n - q;
        H[t] = 0.5f * (T2[p * n + q] + T2[pf * n + q] + T2[p * n + qf] - T2[pf * n + qf]);
    }
    __syncthreads();

    if (t < nn) {
        int fk = (t == 0) ? 0 : nn - t;
        float a = H[t], c = H[fk];
        size_t o = (((size_t)(b * 16 + r)) * CIN + i) * 256 + t;
        Xe[o] = 0.5f * (a + c);
        Xo[o] = 0.5f * (a - c);
    }
}

// dht2 of weights[:, :, :n, :n] for each used n, row-column + correction.
__global__ void k_wt(const float* __restrict__ wts, const int* __restrict__ used,
                     const float* __restrict__ cycN, float* __restrict__ Y) {
    int n = blockIdx.y + 1;
    if (!used[n]) return;
    int io = blockIdx.x;
    int t = threadIdx.x;
    int nn = n * n;
    __shared__ float Wt[256];
    __shared__ float T1[256];
    __shared__ float T2[256];
    __shared__ float cnL[16];
    Wt[t] = wts[(size_t)io * 256 + t];
    if (t < n) cnL[t] = cycN[(n * (n - 1)) / 2 + t];
    __syncthreads();
    int p = 0, q = 0;
    if (t < nn) { p = t / n; q = t - p * n; }
    if (t < nn) {
        float acc = 0.f;
        int idx = 0;
        for (int v = 0; v < n; ++v) {
            acc += Wt[p * 16 + v] * cnL[idx];
            idx += q; if (idx >= n) idx -= n;
        }
        T1[p * n + q] = acc;
    }
    __syncthreads();
    if (t < nn) {
        float acc = 0.f;
        int idx = 0;
        for (int u = 0; u < n; ++u) {
            acc += T1[u * n + q] * cnL[idx];
            idx += p; if (idx >= n) idx -= n;
        }
        T2[t] = acc;
    }
    __syncthreads();
    if (t < nn) {
        int pf = (p == 0) ? 0 : n - p;
        int qf = (q == 0) ? 0 : n - q;
        float v = 0.5f * (T2[p * n + q] + T2[pf * n + q] + T2[p * n + qf] - T2[pf * n + qf]);
        int m = n - 1;
        int ps2 = m * (m + 1) * (2 * m + 1) / 6;  // sum of squares 1..m
        Y[(size_t)1024 * ps2 + (size_t)io * nn + t] = v;
    }
}

// Z[o,k] = sum_i Xe[i,k]*Y[io,k] + Xo[i,k]*Y[io,flip(k)].
// grid (8, 128): blockIdx.x = group of 4 outputs, blockIdx.y = (b,r).
__global__ void k_z(const float* __restrict__ Xe, const float* __restrict__ Xo,
                    const float* __restrict__ Y, const int* __restrict__ nm,
                    float* __restrict__ Z) {
    int br = blockIdx.y;
    int og = blockIdx.x * 4;
    int b = br >> 4, r = br & 15;
    int n = nm[b * 16 + r];
    int nn = n * n;
    int t = threadIdx.x;
    if (t >= nn) return;
    int m = n - 1;
    int ps2 = m * (m + 1) * (2 * m + 1) / 6;
    const float* Yb = Y + (size_t)1024 * ps2;
    int fk = (t == 0) ? 0 : nn - t;
    float acc[4] = {0.f, 0.f, 0.f, 0.f};
    size_t xbase = (size_t)br * CIN * 256;
    for (int i = 0; i < CIN; ++i) {
        float xe = Xe[xbase + i * 256 + t];
        float xo = Xo[xbase + i * 256 + t];
        const float* yi = Yb + (size_t)(i * COUT + og) * nn;
#pragma unroll
        for (int oo = 0; oo < 4; ++oo) {
            acc[oo] += xe * yi[oo * nn + t] + xo * yi[oo * nn + fk];
        }
    }
    size_t zbase = (size_t)br * COUT * 256;
#pragma unroll
    for (int oo = 0; oo < 4; ++oo) Z[zbase + (og + oo) * 256 + t] = acc[oo];
}

// One block per (o, r, b): inverse dht2 via row-column + correction (/n^2),
// then n->64 separable expansion (/4096), float4 heavy stage, write region.
__global__ void k_out(const float* __restrict__ Z, const int* __restrict__ nm,
                      const float* __restrict__ cyc64, const float* __restrict__ cycN,
                      float* __restrict__ out) {
    int o = blockIdx.x, r = blockIdx.y, b = blockIdx.z;
    int n = nm[b * 16 + r];
    int nn = n * n;
    int t = threadIdx.x;
    int br = b * 16 + r;

    __shared__ float Zs[256];
    __shared__ float T1[256];
    __shared__ float T2[256];
    __shared__ float Bk[256];
    __shared__ __align__(16) float E1[16 * 64];
    __shared__ float cyc64L[64];
    __shared__ float cnL[16];

    if (t < 64) cyc64L[t] = cyc64[t];
    if (t < n)  cnL[t] = cycN[(n * (n - 1)) / 2 + t];
    if (t < nn) Zs[t] = Z[((size_t)br * COUT + o) * 256 + t];
    __syncthreads();

    int p = 0, q = 0;
    if (t < nn) { p = t / n; q = t - p * n; }

    // inverse dht2 (row-column + correction), / nn
    if (t < nn) {
        float acc = 0.f;
        int idx = 0;
        for (int v = 0; v < n; ++v) {
            acc += Zs[p * n + v] * cnL[idx];
            idx += q; if (idx >= n) idx -= n;
        }
        T1[p * n + q] = acc;
    }
    __syncthreads();
    if (t < nn) {
        float acc = 0.f;
        int idx = 0;
        for (int u = 0; u < n; ++u) {
            acc += T1[u * n + q] * cnL[idx];
            idx += p; if (idx >= n) idx -= n;
        }
        T2[t] = acc;
    }
    __syncthreads();
    if (t < nn) {
        int pf = (p == 0) ? 0 : n - p;
        int qf = (q == 0) ? 0 : n - q;
        Bk[t] = 0.5f * (T2[p * n + q] + T2[pf * n + q] + T2[p * n + qf] - T2[pf * n + qf])
                / (float)nn;
    }
    __syncthreads();

    // E1[p][v] = sum_q Bk[p*n+q] * cas64(q*v)   (wave-uniform p: Bk read is broadcast)
    for (int mm = t; mm < n * 64; mm += 256) {
        int pp = mm >> 6, v = mm & 63;
        float acc = 0.f;
        int idx = 0;
        for (int qq = 0; qq < n; ++qq) {
            acc += Bk[pp * n + qq] * cyc64L[idx];
            idx = (idx + v) & 63;
        }
        E1[pp * 64 + v] = acc;
    }
    __syncthreads();

    // out[u][v] = (1/4096) sum_p E1[p][v] * cas64(p*u); float4 over v.
    int ri = r >> 2, rj = r & 3;
    float* ob = out + (((size_t)(b * COUT + o)) * SS + ri * REG) * SS + rj * REG;
    const float4* E14 = (const float4*)E1;
    const float inv = 1.0f / 4096.0f;
    int u0 = t >> 4, vg = t & 15;
    for (int it = 0; it < 4; ++it) {
        int u = it * 16 + u0;
        float4 acc = {0.f, 0.f, 0.f, 0.f};
        int idx = 0;
        for (int pp = 0; pp < n; ++pp) {
            float c = cyc64L[idx]; idx = (idx + u) & 63;
            float4 e = E14[pp * 16 + vg];
            acc.x += c * e.x; acc.y += c * e.y;
            acc.z += c * e.z; acc.w += c * e.w;
        }
        acc.x *= inv; acc.y *= inv; acc.z *= inv; acc.w *= inv;
        *(float4*)(ob + (size_t)u * SS + vg * 4) = acc;
    }
}

extern "C" void kernel_launch(void* const* d_in, const int* in_sizes, int n_in,
                              void* d_out, int out_size, void* d_ws, size_t ws_size,
                              hipStream_t stream) {
    const float* x   = (const float*)d_in[0];
    const float* err = (const float*)d_in[1];
    const float* wts = (const float*)d_in[2];
    float* out = (float*)d_out;
    char* ws = (char*)d_ws;

    float* avg   = (float*)(ws + AVG_OFF);
    int*   nm    = (int*)  (ws + NM_OFF);
    int*   used  = (int*)  (ws + USED_OFF);
    float* cyc64 = (float*)(ws + C64_OFF);
    float* cycN  = (float*)(ws + CN_OFF);
    float* Y     = (float*)(ws + Y_OFF);
    float* Xe    = (float*)(ws + XE_OFF);
    float* Xo    = (float*)(ws + XO_OFF);
    float* Z     = (float*)(ws + Z_OFF);

    k_tables<<<1, 256, 0, stream>>>(cyc64, cycN);
    k_avg<<<dim3(16, NB), 256, 0, stream>>>(err, avg);
    k_nm<<<1, 32, 0, stream>>>(avg, nm, used);
    k_fwd<<<dim3(CIN, 16, NB), 256, 0, stream>>>(x, nm, cyc64, cycN, Xe, Xo);
    k_wt<<<dim3(CIN * COUT, NMAX), 256, 0, stream>>>(wts, used, cycN, Y);
    k_z<<<dim3(8, 128), 256, 0, stream>>>(Xe, Xo, Y, nm, Z);
    k_out<<<dim3(COUT, 16, NB), 256, 0, stream>>>(Z, nm, cyc64, cycN, out);
}